// Round 2
// baseline (1695.704 us; speedup 1.0000x reference)
//
#include <hip/hip_runtime.h>
#include <hip/hip_fp16.h>
#include <hip/hip_bf16.h>

// Problem constants (from reference)
//   N=50000, E=800000, IN=OUT=128, H=4, C=32, TOKEN=768, OPTION=4, NGRAPH=256
//   groups = 256/4 = 64
//
// Decomposition:
//   alpha*3*sqrt(C) = (Q_i+S_i).K_j + Q_i.S_j  =  Q_i.K_j + S_i.K_j + Q_i.S_j
//   where S_i = Sg[batch[i]>>2] has only 64 distinct rows -> LDS table.
//   Global softmax needs no max-subtraction (|alpha| << 1): scatter
//   unnormalized p*V, track per-head sum(p), normalize in the output GEMM.

// ---------- pack element load/store helpers (fp32 or fp16 scratch) ----------
__device__ __forceinline__ float4 ld4(const float* p, int i) {
    return ((const float4*)p)[i];
}
__device__ __forceinline__ float4 ld4(const __half* p, int i) {
    float2 raw = ((const float2*)p)[i];           // 8 B = 4 halves
    union { float2 f; __half2 h[2]; } u; u.f = raw;
    float2 a = __half22float2(u.h[0]);
    float2 b = __half22float2(u.h[1]);
    return make_float4(a.x, a.y, b.x, b.y);
}
__device__ __forceinline__ void st1(float* p, float v) { *p = v; }
__device__ __forceinline__ void st1(__half* p, float v) { *p = __float2half_rn(v); }

// ---------------------------------------------------------------------------
// Kernel 1: Sg[64][128] = sentence_embeddings[64][768] @ Ws + bs
// ---------------------------------------------------------------------------
__global__ void k_sgemm(const float* __restrict__ sent, const float* __restrict__ Ws,
                        const float* __restrict__ bs, float* __restrict__ Sg) {
    int g = blockIdx.x;      // 0..63
    int o = threadIdx.x;     // 0..127
    const float* s = sent + g * 768;
    float acc = 0.f;
    #pragma unroll 8
    for (int k = 0; k < 768; ++k) acc += s[k] * Ws[k * 128 + o];
    Sg[g * 128 + o] = acc + bs[o];
}

// ---------------------------------------------------------------------------
// Kernel 2: pack[i] = { Q_i(128), K_i(128), V_i(128) }, group8[i] = batch[i]>>2
// Block: 256 threads, 32 rows per block; x rows staged in LDS.
// ---------------------------------------------------------------------------
template <typename T>
__global__ __launch_bounds__(256) void k_qkv(
    const float* __restrict__ x, const int* __restrict__ batch,
    const float* __restrict__ Wq, const float* __restrict__ bq,
    const float* __restrict__ Wk, const float* __restrict__ bk,
    const float* __restrict__ Wv, const float* __restrict__ bv,
    T* __restrict__ pack, unsigned char* __restrict__ group8, int N) {
    __shared__ float4 xs[32][32];   // 32 rows x 128 ch, 16 KB

    const int row0 = blockIdx.x * 32;
    const int tid = threadIdx.x;

    for (int i = tid; i < 32 * 32; i += 256) {
        int r = i >> 5, k4 = i & 31;
        int row = row0 + r;
        float4 v = make_float4(0.f, 0.f, 0.f, 0.f);
        if (row < N) v = ((const float4*)x)[(size_t)row * 32 + k4];
        xs[r][k4] = v;
    }
    if (tid < 32) {
        int row = row0 + tid;
        if (row < N) group8[row] = (unsigned char)(batch[row] >> 2);
    }
    __syncthreads();

    const int o = tid & 127;
    const int half_ = tid >> 7;   // rows [0..15] or [16..31]

    const float* Wm[3] = {Wq, Wk, Wv};
    const float* bm[3] = {bq, bk, bv};

    #pragma unroll
    for (int m = 0; m < 3; ++m) {
        const float* __restrict__ W = Wm[m];
        float acc[16];
        #pragma unroll
        for (int r = 0; r < 16; ++r) acc[r] = 0.f;
        for (int k4 = 0; k4 < 32; ++k4) {
            float w0 = W[(k4 * 4 + 0) * 128 + o];
            float w1 = W[(k4 * 4 + 1) * 128 + o];
            float w2 = W[(k4 * 4 + 2) * 128 + o];
            float w3 = W[(k4 * 4 + 3) * 128 + o];
            #pragma unroll
            for (int r = 0; r < 16; ++r) {
                float4 xv = xs[half_ * 16 + r][k4];
                acc[r] += xv.x * w0 + xv.y * w1 + xv.z * w2 + xv.w * w3;
            }
        }
        float b = bm[m][o];
        #pragma unroll
        for (int r = 0; r < 16; ++r) {
            int row = row0 + half_ * 16 + r;
            if (row >= N) continue;
            st1(&pack[(size_t)row * 384 + m * 128 + o], acc[r] + b);
        }
    }
}

// ---------------------------------------------------------------------------
// Kernel 3 (fused edge phase), 32 lanes per edge (lane l: head h=l>>3, q=l&7):
//   t = Q_row.K_col + Sg[g_row].K_col + Q_row.Sg[g_col]
//   p = exp(leaky_relu(t/(3*sqrt(C))))
//   outacc[row] += p*V_col (atomics); head_sum[h] += p (double atomics)
// ---------------------------------------------------------------------------
template <typename T>
__global__ __launch_bounds__(256) void k_edge(
    const int* __restrict__ eidx, const T* __restrict__ pack,
    const unsigned char* __restrict__ group8, const float* __restrict__ Sg,
    float* __restrict__ outacc, double* __restrict__ head_sum, int E) {
    __shared__ float4 sg[64 * 32];   // Sg as float4, 32 KB
    __shared__ float hsum[4];

    const int tid = threadIdx.x;
    for (int i = tid; i < 64 * 32; i += 256) sg[i] = ((const float4*)Sg)[i];
    if (tid < 4) hsum[tid] = 0.f;
    __syncthreads();

    const int slot = tid >> 5;    // 8 edges per block-iteration
    const int l = tid & 31;
    const int h = l >> 3;         // head 0..3
    const int q = l & 7;          // float4 chunk within head
    const int idx = h * 8 + q;    // channel float4 index 0..31

    const float inv_scale = 0.05892556509887896f;  // 1/(3*sqrt(32))
    float lsum = 0.f;

    for (long long base = (long long)blockIdx.x * 8; base < E;
         base += (long long)gridDim.x * 8) {
        int e = (int)base + slot;
        if (e < E) {
            int row = eidx[e];
            int col = eidx[E + e];
            const T* rp = pack + (size_t)row * 384;
            const T* cp = pack + (size_t)col * 384;
            float4 qq = ld4(rp, idx);          // Q_row chunk
            float4 kk = ld4(cp, 32 + idx);     // K_col chunk
            float4 vv = ld4(cp, 64 + idx);     // V_col chunk
            float4 sr = sg[group8[row] * 32 + idx];
            float4 sc = sg[group8[col] * 32 + idx];
            float t = qq.x * kk.x + qq.y * kk.y + qq.z * kk.z + qq.w * kk.w
                    + sr.x * kk.x + sr.y * kk.y + sr.z * kk.z + sr.w * kk.w
                    + qq.x * sc.x + qq.y * sc.y + qq.z * sc.z + qq.w * sc.w;
            t += __shfl_xor(t, 1);
            t += __shfl_xor(t, 2);
            t += __shfl_xor(t, 4);
            float a = t * inv_scale;
            a = (a >= 0.f) ? a : 0.2f * a;     // leaky_relu(0.2)
            float p = expf(a);
            if (q == 0) lsum += p;
            float* dst = outacc + (size_t)row * 128 + h * 32 + q * 4;
            atomicAdd(dst + 0, p * vv.x);
            atomicAdd(dst + 1, p * vv.y);
            atomicAdd(dst + 2, p * vv.z);
            atomicAdd(dst + 3, p * vv.w);
        }
    }
    if (q == 0) atomicAdd(&hsum[h], lsum);
    __syncthreads();
    if (tid < 4) atomicAdd(&head_sum[tid], (double)hsum[tid]);
}

// ---------------------------------------------------------------------------
// Kernel 4: out = (outacc * (1/head_sum)) @ Wo + bo + x
// outacc aliases d_out; each block touches only its own 32 rows (LDS-staged
// before overwrite) -> no cross-block hazard.
// ---------------------------------------------------------------------------
__global__ __launch_bounds__(256) void k_out(
    const float* __restrict__ outacc, const double* __restrict__ head_sum,
    const float* __restrict__ Wo, const float* __restrict__ bo,
    const float* __restrict__ x, float* __restrict__ out, int N) {
    __shared__ float4 ys[32][32];

    const int row0 = blockIdx.x * 32;
    const int tid = threadIdx.x;

    float inv[4];
    #pragma unroll
    for (int hh = 0; hh < 4; ++hh) inv[hh] = (float)(1.0 / head_sum[hh]);

    for (int i = tid; i < 32 * 32; i += 256) {
        int r = i >> 5, k4 = i & 31;
        int row = row0 + r;
        float4 v = make_float4(0.f, 0.f, 0.f, 0.f);
        if (row < N) v = ((const float4*)outacc)[(size_t)row * 32 + k4];
        float s = inv[k4 >> 3];     // head = k4/8
        v.x *= s; v.y *= s; v.z *= s; v.w *= s;
        ys[r][k4] = v;
    }
    __syncthreads();

    const int o = tid & 127;
    const int half_ = tid >> 7;
    float acc[16];
    #pragma unroll
    for (int r = 0; r < 16; ++r) acc[r] = 0.f;
    for (int k4 = 0; k4 < 32; ++k4) {
        float w0 = Wo[(k4 * 4 + 0) * 128 + o];
        float w1 = Wo[(k4 * 4 + 1) * 128 + o];
        float w2 = Wo[(k4 * 4 + 2) * 128 + o];
        float w3 = Wo[(k4 * 4 + 3) * 128 + o];
        #pragma unroll
        for (int r = 0; r < 16; ++r) {
            float4 yv = ys[half_ * 16 + r][k4];
            acc[r] += yv.x * w0 + yv.y * w1 + yv.z * w2 + yv.w * w3;
        }
    }
    float b = bo[o];
    #pragma unroll
    for (int r = 0; r < 16; ++r) {
        int row = row0 + half_ * 16 + r;
        if (row < N)
            out[(size_t)row * 128 + o] = acc[r] + b + x[(size_t)row * 128 + o];
    }
}

// ---------------------------------------------------------------------------
extern "C" void kernel_launch(void* const* d_in, const int* in_sizes, int n_in,
                              void* d_out, int out_size, void* d_ws, size_t ws_size,
                              hipStream_t stream) {
    const float* x     = (const float*)d_in[0];
    const int*   eidx  = (const int*)d_in[1];
    const float* sent  = (const float*)d_in[2];
    const int*   batch = (const int*)d_in[3];
    const float* Wq = (const float*)d_in[4];
    const float* bq = (const float*)d_in[5];
    const float* Wk = (const float*)d_in[6];
    const float* bk = (const float*)d_in[7];
    const float* Wv = (const float*)d_in[8];
    const float* bv = (const float*)d_in[9];
    const float* Ws = (const float*)d_in[10];
    const float* bs = (const float*)d_in[11];
    const float* Wo = (const float*)d_in[12];
    const float* bo = (const float*)d_in[13];

    const int N = in_sizes[0] / 128;   // 50000
    const int E = in_sizes[1] / 2;     // 800000

    // workspace layout (16B-aligned slots)
    char* ws = (char*)d_ws;
    float*  Sg       = (float*)ws;                        // 32768 B
    double* head_sum = (double*)(ws + 32768);             // 32 B
    unsigned char* group8 = (unsigned char*)(ws + 33024); // N bytes
    size_t off = 33024 + (((size_t)N + 255) & ~(size_t)255);
    // pack: {Q,K,V} = 384 elems/node; fp32 if it fits in ws, else fp16
    size_t need_f32 = off + (size_t)N * 384 * sizeof(float);
    bool use_f32 = (ws_size >= need_f32);

    float* outacc = (float*)d_out;     // aliases d_out (disjoint rows in k_out)

    hipMemsetAsync(outacc, 0, (size_t)N * 128 * sizeof(float), stream);
    hipMemsetAsync(head_sum, 0, 4 * sizeof(double), stream);

    k_sgemm<<<64, 128, 0, stream>>>(sent, Ws, bs, Sg);

    const int qkv_blocks = (N + 31) / 32;
    if (use_f32) {
        float* pack = (float*)(ws + off);
        k_qkv<float><<<qkv_blocks, 256, 0, stream>>>(x, batch, Wq, bq, Wk, bk,
                                                     Wv, bv, pack, group8, N);
        k_edge<float><<<2048, 256, 0, stream>>>(eidx, pack, group8, Sg,
                                                outacc, head_sum, E);
    } else {
        __half* pack = (__half*)(ws + off);
        k_qkv<__half><<<qkv_blocks, 256, 0, stream>>>(x, batch, Wq, bq, Wk, bk,
                                                      Wv, bv, pack, group8, N);
        k_edge<__half><<<2048, 256, 0, stream>>>(eidx, pack, group8, Sg,
                                                 outacc, head_sum, E);
    }

    k_out<<<qkv_blocks, 256, 0, stream>>>(outacc, head_sum, Wo, bo, x,
                                          (float*)d_out, N);
}

// Round 7
// 785.937 us; speedup vs baseline: 2.1576x; 2.1576x over previous
//
#include <hip/hip_runtime.h>
#include <hip/hip_fp16.h>
#include <hip/hip_bf16.h>

// Problem constants: N=50000, E=800000, IN=OUT=128, H=4, C=32, TOKEN=768,
// OPTION=4, NGRAPH=256 -> 64 sentence groups.
//
// alpha*3*sqrt(C) = (Q_i+S_i).K_j + Q_i.S_j ; S_i = Sg[batch[i]>>2] (64 rows).
// Global softmax over all edges per head; |alpha| << 1 so no max pass needed:
// scatter unnormalized p*V, track per-head sum(p), normalize in final GEMM.
//
// CSR by destination row (histogram/scan/scatter) then one WAVE per row
// accumulating p*V in registers -> zero per-edge global atomics.

// ---------- pack element load helpers (fp32 or fp16 scratch) ----------
__device__ __forceinline__ float2 ld2(const float* p, int i) {
    return ((const float2*)p)[i];
}
__device__ __forceinline__ float2 ld2(const __half* p, int i) {
    return __half22float2(((const __half2*)p)[i]);
}
__device__ __forceinline__ void st1(float* p, float v) { *p = v; }
__device__ __forceinline__ void st1(__half* p, float v) { *p = __float2half_rn(v); }

// ---------------------------------------------------------------------------
// Kernel 1: Sg[64][128] = sentence_embeddings[64][768] @ Ws + bs
// ---------------------------------------------------------------------------
__global__ void k_sgemm(const float* __restrict__ sent, const float* __restrict__ Ws,
                        const float* __restrict__ bs, float* __restrict__ Sg) {
    int g = blockIdx.x;      // 0..63
    int o = threadIdx.x;     // 0..127
    const float* s = sent + g * 768;
    float acc = 0.f;
    #pragma unroll 8
    for (int k = 0; k < 768; ++k) acc += s[k] * Ws[k * 128 + o];
    Sg[g * 128 + o] = acc + bs[o];
}

// ---------------------------------------------------------------------------
// Kernel 2: pack[i] = { Q_i(128), K_i(128), V_i(128) }, group8[i] = batch[i]>>2
// ---------------------------------------------------------------------------
template <typename T>
__global__ __launch_bounds__(256) void k_qkv(
    const float* __restrict__ x, const int* __restrict__ batch,
    const float* __restrict__ Wq, const float* __restrict__ bq,
    const float* __restrict__ Wk, const float* __restrict__ bk,
    const float* __restrict__ Wv, const float* __restrict__ bv,
    T* __restrict__ pack, unsigned char* __restrict__ group8, int N) {
    __shared__ float4 xs[32][32];   // 32 rows x 128 ch, 16 KB

    const int row0 = blockIdx.x * 32;
    const int tid = threadIdx.x;

    for (int i = tid; i < 32 * 32; i += 256) {
        int r = i >> 5, k4 = i & 31;
        int row = row0 + r;
        float4 v = make_float4(0.f, 0.f, 0.f, 0.f);
        if (row < N) v = ((const float4*)x)[(size_t)row * 32 + k4];
        xs[r][k4] = v;
    }
    if (tid < 32) {
        int row = row0 + tid;
        if (row < N) group8[row] = (unsigned char)(batch[row] >> 2);
    }
    __syncthreads();

    const int o = tid & 127;
    const int half_ = tid >> 7;

    const float* Wm[3] = {Wq, Wk, Wv};
    const float* bm[3] = {bq, bk, bv};

    #pragma unroll
    for (int m = 0; m < 3; ++m) {
        const float* __restrict__ W = Wm[m];
        float acc[16];
        #pragma unroll
        for (int r = 0; r < 16; ++r) acc[r] = 0.f;
        for (int k4 = 0; k4 < 32; ++k4) {
            float w0 = W[(k4 * 4 + 0) * 128 + o];
            float w1 = W[(k4 * 4 + 1) * 128 + o];
            float w2 = W[(k4 * 4 + 2) * 128 + o];
            float w3 = W[(k4 * 4 + 3) * 128 + o];
            #pragma unroll
            for (int r = 0; r < 16; ++r) {
                float4 xv = xs[half_ * 16 + r][k4];
                acc[r] += xv.x * w0 + xv.y * w1 + xv.z * w2 + xv.w * w3;
            }
        }
        float b = bm[m][o];
        #pragma unroll
        for (int r = 0; r < 16; ++r) {
            int row = row0 + half_ * 16 + r;
            if (row >= N) continue;
            st1(&pack[(size_t)row * 384 + m * 128 + o], acc[r] + b);
        }
    }
}

// ---------------------------------------------------------------------------
// CSR build: histogram -> exclusive scan -> scatter cols by destination row
// ---------------------------------------------------------------------------
__global__ __launch_bounds__(256) void k_hist(const int* __restrict__ eidx,
                                              int* __restrict__ counts, int E) {
    int e = blockIdx.x * 256 + threadIdx.x;
    if (e < E) atomicAdd(&counts[eidx[e]], 1);
}

__global__ __launch_bounds__(1024) void k_scan(const int* __restrict__ counts,
                                               int* __restrict__ row_start,
                                               int* __restrict__ cursor, int N) {
    __shared__ int part[1024];
    const int tid = threadIdx.x;
    const int chunk = (N + 1023) >> 10;
    const int lo = tid * chunk;
    const int hi = min(lo + chunk, N);
    int s = 0;
    for (int i = lo; i < hi; ++i) s += counts[i];
    part[tid] = s;
    __syncthreads();
    for (int d = 1; d < 1024; d <<= 1) {
        int v = 0;
        if (tid >= d) v = part[tid - d];
        __syncthreads();
        if (tid >= d) part[tid] += v;
        __syncthreads();
    }
    int run = (tid == 0) ? 0 : part[tid - 1];
    for (int i = lo; i < hi; ++i) {
        row_start[i] = run;
        cursor[i] = run;
        run += counts[i];
    }
    if (tid == 0) row_start[N] = part[1023];
}

__global__ __launch_bounds__(256) void k_scatter(const int* __restrict__ eidx,
                                                 int* __restrict__ cursor,
                                                 int* __restrict__ csr_col, int E) {
    int e = blockIdx.x * 256 + threadIdx.x;
    if (e < E) {
        int row = eidx[e];
        int col = eidx[E + e];
        int pos = atomicAdd(&cursor[row], 1);
        csr_col[pos] = col;
    }
}

// ---------------------------------------------------------------------------
// Kernel 3: one wave per destination row. Lane l owns channels {2l, 2l+1}.
// Head of lane l is l>>4 (channels 32h..32h+31 <-> lanes 16h..16h+15).
//   t = (Q+S)_row . K_col + Q_row . Sg[g_col]     (reduce over 16-lane group)
//   p = exp(leaky_relu(t/(3*sqrt(C))));  acc += p*V_col  (registers)
// Row written once; per-head sum(p) via LDS + one double atomic per block.
// ---------------------------------------------------------------------------
template <typename T>
__global__ __launch_bounds__(256) void k_rowedge(
    const int* __restrict__ csr_col, const int* __restrict__ row_start,
    const T* __restrict__ pack, const unsigned char* __restrict__ group8,
    const float* __restrict__ Sg, float* __restrict__ outacc,
    double* __restrict__ head_sum, int N) {
    __shared__ float2 sg[64 * 64];   // Sg as float2[group][lane], 32 KB
    __shared__ float hsum[4];

    const int tid = threadIdx.x;
    for (int i = tid; i < 64 * 64; i += 256) sg[i] = ((const float2*)Sg)[i];
    if (tid < 4) hsum[tid] = 0.f;
    __syncthreads();

    const int wid = tid >> 6;
    const int l = tid & 63;
    const int row = blockIdx.x * 4 + wid;

    const float inv_scale = 0.05892556509887896f;  // 1/(3*sqrt(32))
    float lsum = 0.f;

    if (row < N) {
        float2 q = ld2(pack + (size_t)row * 384, l);
        float2 sr = sg[(int)group8[row] * 64 + l];
        float2 qs = make_float2(q.x + sr.x, q.y + sr.y);
        float2 acc = make_float2(0.f, 0.f);

        const int beg = row_start[row];
        const int end = row_start[row + 1];
        for (int idx = beg; idx < end; ++idx) {
            int col = csr_col[idx];
            const T* cp = pack + (size_t)col * 384;
            float2 kk = ld2(cp + 128, l);
            float2 vv = ld2(cp + 256, l);
            float2 sc = sg[(int)group8[col] * 64 + l];
            float t = qs.x * kk.x + qs.y * kk.y + q.x * sc.x + q.y * sc.y;
            t += __shfl_xor(t, 1);
            t += __shfl_xor(t, 2);
            t += __shfl_xor(t, 4);
            t += __shfl_xor(t, 8);
            float a = t * inv_scale;
            a = (a >= 0.f) ? a : 0.2f * a;       // leaky_relu(0.2)
            float p = expf(a);
            if ((l & 15) == 0) lsum += p;
            acc.x += p * vv.x;
            acc.y += p * vv.y;
        }
        ((float2*)outacc)[(size_t)row * 64 + l] = acc;
    }

    if ((l & 15) == 0) atomicAdd(&hsum[l >> 4], lsum);
    __syncthreads();
    if (tid < 4) atomicAdd(&head_sum[tid], (double)hsum[tid]);
}

// ---------------------------------------------------------------------------
// Kernel 4: out = (outacc * (1/head_sum)) @ Wo + bo + x
// outacc aliases d_out; each block stages only its own 32 rows -> safe.
// ---------------------------------------------------------------------------
__global__ __launch_bounds__(256) void k_out(
    const float* __restrict__ outacc, const double* __restrict__ head_sum,
    const float* __restrict__ Wo, const float* __restrict__ bo,
    const float* __restrict__ x, float* __restrict__ out, int N) {
    __shared__ float4 ys[32][32];

    const int row0 = blockIdx.x * 32;
    const int tid = threadIdx.x;

    float inv[4];
    #pragma unroll
    for (int hh = 0; hh < 4; ++hh) inv[hh] = (float)(1.0 / head_sum[hh]);

    for (int i = tid; i < 32 * 32; i += 256) {
        int r = i >> 5, k4 = i & 31;
        int row = row0 + r;
        float4 v = make_float4(0.f, 0.f, 0.f, 0.f);
        if (row < N) v = ((const float4*)outacc)[(size_t)row * 32 + k4];
        float s = inv[k4 >> 3];
        v.x *= s; v.y *= s; v.z *= s; v.w *= s;
        ys[r][k4] = v;
    }
    __syncthreads();

    const int o = tid & 127;
    const int half_ = tid >> 7;
    float acc[16];
    #pragma unroll
    for (int r = 0; r < 16; ++r) acc[r] = 0.f;
    for (int k4 = 0; k4 < 32; ++k4) {
        float w0 = Wo[(k4 * 4 + 0) * 128 + o];
        float w1 = Wo[(k4 * 4 + 1) * 128 + o];
        float w2 = Wo[(k4 * 4 + 2) * 128 + o];
        float w3 = Wo[(k4 * 4 + 3) * 128 + o];
        #pragma unroll
        for (int r = 0; r < 16; ++r) {
            float4 yv = ys[half_ * 16 + r][k4];
            acc[r] += yv.x * w0 + yv.y * w1 + yv.z * w2 + yv.w * w3;
        }
    }
    float b = bo[o];
    #pragma unroll
    for (int r = 0; r < 16; ++r) {
        int row = row0 + half_ * 16 + r;
        if (row < N)
            out[(size_t)row * 128 + o] = acc[r] + b + x[(size_t)row * 128 + o];
    }
}

// ---------------------------------------------------------------------------
extern "C" void kernel_launch(void* const* d_in, const int* in_sizes, int n_in,
                              void* d_out, int out_size, void* d_ws, size_t ws_size,
                              hipStream_t stream) {
    const float* x     = (const float*)d_in[0];
    const int*   eidx  = (const int*)d_in[1];
    const float* sent  = (const float*)d_in[2];
    const int*   batch = (const int*)d_in[3];
    const float* Wq = (const float*)d_in[4];
    const float* bq = (const float*)d_in[5];
    const float* Wk = (const float*)d_in[6];
    const float* bk = (const float*)d_in[7];
    const float* Wv = (const float*)d_in[8];
    const float* bv = (const float*)d_in[9];
    const float* Ws = (const float*)d_in[10];
    const float* bs = (const float*)d_in[11];
    const float* Wo = (const float*)d_in[12];
    const float* bo = (const float*)d_in[13];

    const int N = in_sizes[0] / 128;   // 50000
    const int E = in_sizes[1] / 2;     // 800000

    // ---- workspace layout (256B-aligned slots) ----
    char* ws = (char*)d_ws;
    size_t off = 0;
    auto alloc = [&](size_t bytes) {
        char* p = ws + off;
        off += (bytes + 255) & ~(size_t)255;
        return p;
    };
    float*  Sg        = (float*)alloc(64 * 128 * sizeof(float));   // 32 KB
    double* head_sum  = (double*)alloc(4 * sizeof(double));
    unsigned char* group8 = (unsigned char*)alloc((size_t)N);
    int* counts    = (int*)alloc((size_t)N * sizeof(int));
    int* row_start = (int*)alloc(((size_t)N + 1) * sizeof(int));
    int* cursor    = (int*)alloc((size_t)N * sizeof(int));
    int* csr_col   = (int*)alloc((size_t)E * sizeof(int));
    size_t pack_off = off;
    size_t need_f32 = pack_off + (size_t)N * 384 * sizeof(float);
    bool use_f32 = (ws_size >= need_f32);

    float* outacc = (float*)d_out;   // aliased; k_rowedge writes every row once

    hipMemsetAsync(counts, 0, (size_t)N * sizeof(int), stream);
    hipMemsetAsync(head_sum, 0, 4 * sizeof(double), stream);

    k_sgemm<<<64, 128, 0, stream>>>(sent, Ws, bs, Sg);

    const int eb = (E + 255) / 256;
    k_hist<<<eb, 256, 0, stream>>>(eidx, counts, E);
    k_scan<<<1, 1024, 0, stream>>>(counts, row_start, cursor, N);
    k_scatter<<<eb, 256, 0, stream>>>(eidx, cursor, csr_col, E);

    const int qkv_blocks = (N + 31) / 32;
    const int row_blocks = (N + 3) / 4;
    if (use_f32) {
        float* pack = (float*)(ws + pack_off);
        k_qkv<float><<<qkv_blocks, 256, 0, stream>>>(x, batch, Wq, bq, Wk, bk,
                                                     Wv, bv, pack, group8, N);
        k_rowedge<float><<<row_blocks, 256, 0, stream>>>(csr_col, row_start, pack,
                                                         group8, Sg, outacc,
                                                         head_sum, N);
    } else {
        __half* pack = (__half*)(ws + pack_off);
        k_qkv<__half><<<qkv_blocks, 256, 0, stream>>>(x, batch, Wq, bq, Wk, bk,
                                                      Wv, bv, pack, group8, N);
        k_rowedge<__half><<<row_blocks, 256, 0, stream>>>(csr_col, row_start, pack,
                                                          group8, Sg, outacc,
                                                          head_sum, N);
    }

    k_out<<<qkv_blocks, 256, 0, stream>>>(outacc, head_sum, Wo, bo, x,
                                          (float*)d_out, N);
}

// Round 8
// 626.827 us; speedup vs baseline: 2.7052x; 1.2538x over previous
//
#include <hip/hip_runtime.h>
#include <hip/hip_fp16.h>
#include <hip/hip_bf16.h>

// Problem constants: N=50000, E=800000, IN=OUT=128, H=4, C=32, TOKEN=768,
// OPTION=4, NGRAPH=256 -> 64 sentence groups.
//
// alpha*3*sqrt(C) = (Q_i+S_i).K_j + Q_i.S_j ; S_i = Sg[batch[i]>>2] (64 rows).
// Global softmax over all edges per head; |alpha| << 1 so no max pass needed:
// scatter unnormalized p*V, track per-head sum(p), normalize in final GEMM.
//
// CSR by destination row, one wave per row. Round-8 change (k_rowedge only):
// 2 edges per wave (32 lanes x float4 each) + unroll-2 per half (4 gather
// chains in flight) + 512-thread blocks (LDS table shared by 8 waves).

// ---------- pack element helpers (fp32 or fp16 scratch) ----------
__device__ __forceinline__ float4 ld4(const float* p, int i) {
    return ((const float4*)p)[i];
}
__device__ __forceinline__ float4 ld4(const __half* p, int i) {
    __half2 h01 = ((const __half2*)p)[2 * i];
    __half2 h23 = ((const __half2*)p)[2 * i + 1];
    float2 a = __half22float2(h01);
    float2 b = __half22float2(h23);
    return make_float4(a.x, a.y, b.x, b.y);
}
__device__ __forceinline__ void st1(float* p, float v) { *p = v; }
__device__ __forceinline__ void st1(__half* p, float v) { *p = __float2half_rn(v); }

// ---------------------------------------------------------------------------
// Kernel 1: Sg[64][128] = sentence_embeddings[64][768] @ Ws + bs
// ---------------------------------------------------------------------------
__global__ void k_sgemm(const float* __restrict__ sent, const float* __restrict__ Ws,
                        const float* __restrict__ bs, float* __restrict__ Sg) {
    int g = blockIdx.x;      // 0..63
    int o = threadIdx.x;     // 0..127
    const float* s = sent + g * 768;
    float acc = 0.f;
    #pragma unroll 8
    for (int k = 0; k < 768; ++k) acc += s[k] * Ws[k * 128 + o];
    Sg[g * 128 + o] = acc + bs[o];
}

// ---------------------------------------------------------------------------
// Kernel 2: pack[i] = { Q_i(128), K_i(128), V_i(128) }, group8[i] = batch[i]>>2
// ---------------------------------------------------------------------------
template <typename T>
__global__ __launch_bounds__(256) void k_qkv(
    const float* __restrict__ x, const int* __restrict__ batch,
    const float* __restrict__ Wq, const float* __restrict__ bq,
    const float* __restrict__ Wk, const float* __restrict__ bk,
    const float* __restrict__ Wv, const float* __restrict__ bv,
    T* __restrict__ pack, unsigned char* __restrict__ group8, int N) {
    __shared__ float4 xs[32][32];   // 32 rows x 128 ch, 16 KB

    const int row0 = blockIdx.x * 32;
    const int tid = threadIdx.x;

    for (int i = tid; i < 32 * 32; i += 256) {
        int r = i >> 5, k4 = i & 31;
        int row = row0 + r;
        float4 v = make_float4(0.f, 0.f, 0.f, 0.f);
        if (row < N) v = ((const float4*)x)[(size_t)row * 32 + k4];
        xs[r][k4] = v;
    }
    if (tid < 32) {
        int row = row0 + tid;
        if (row < N) group8[row] = (unsigned char)(batch[row] >> 2);
    }
    __syncthreads();

    const int o = tid & 127;
    const int half_ = tid >> 7;

    const float* Wm[3] = {Wq, Wk, Wv};
    const float* bm[3] = {bq, bk, bv};

    #pragma unroll
    for (int m = 0; m < 3; ++m) {
        const float* __restrict__ W = Wm[m];
        float acc[16];
        #pragma unroll
        for (int r = 0; r < 16; ++r) acc[r] = 0.f;
        for (int k4 = 0; k4 < 32; ++k4) {
            float w0 = W[(k4 * 4 + 0) * 128 + o];
            float w1 = W[(k4 * 4 + 1) * 128 + o];
            float w2 = W[(k4 * 4 + 2) * 128 + o];
            float w3 = W[(k4 * 4 + 3) * 128 + o];
            #pragma unroll
            for (int r = 0; r < 16; ++r) {
                float4 xv = xs[half_ * 16 + r][k4];
                acc[r] += xv.x * w0 + xv.y * w1 + xv.z * w2 + xv.w * w3;
            }
        }
        float b = bm[m][o];
        #pragma unroll
        for (int r = 0; r < 16; ++r) {
            int row = row0 + half_ * 16 + r;
            if (row >= N) continue;
            st1(&pack[(size_t)row * 384 + m * 128 + o], acc[r] + b);
        }
    }
}

// ---------------------------------------------------------------------------
// CSR build: histogram -> exclusive scan -> scatter cols by destination row
// ---------------------------------------------------------------------------
__global__ __launch_bounds__(256) void k_hist(const int* __restrict__ eidx,
                                              int* __restrict__ counts, int E) {
    int e = blockIdx.x * 256 + threadIdx.x;
    if (e < E) atomicAdd(&counts[eidx[e]], 1);
}

__global__ __launch_bounds__(1024) void k_scan(const int* __restrict__ counts,
                                               int* __restrict__ row_start,
                                               int* __restrict__ cursor, int N) {
    __shared__ int part[1024];
    const int tid = threadIdx.x;
    const int chunk = (N + 1023) >> 10;
    const int lo = tid * chunk;
    const int hi = min(lo + chunk, N);
    int s = 0;
    for (int i = lo; i < hi; ++i) s += counts[i];
    part[tid] = s;
    __syncthreads();
    for (int d = 1; d < 1024; d <<= 1) {
        int v = 0;
        if (tid >= d) v = part[tid - d];
        __syncthreads();
        if (tid >= d) part[tid] += v;
        __syncthreads();
    }
    int run = (tid == 0) ? 0 : part[tid - 1];
    for (int i = lo; i < hi; ++i) {
        row_start[i] = run;
        cursor[i] = run;
        run += counts[i];
    }
    if (tid == 0) row_start[N] = part[1023];
}

__global__ __launch_bounds__(256) void k_scatter(const int* __restrict__ eidx,
                                                 int* __restrict__ cursor,
                                                 int* __restrict__ csr_col, int E) {
    int e = blockIdx.x * 256 + threadIdx.x;
    if (e < E) {
        int row = eidx[e];
        int col = eidx[E + e];
        int pos = atomicAdd(&cursor[row], 1);
        csr_col[pos] = col;
    }
}

// ---------------------------------------------------------------------------
// Kernel 3: one wave per destination row; the wave's two 32-lane halves each
// own an interleaved stream of that row's edges, unrolled x2 (4 gather chains
// in flight). Lane hl (=l&31) owns channels [4hl, 4hl+3]; head = hl>>3
// (8 lanes/head -> 3-level shfl reduce).
//   t = (Q+S)_row . K_col + Q_row . Sg[g_col]
//   p = exp(leaky_relu(t/(3*sqrt(C))));  acc += p*V_col  (registers)
// Halves combined via shfl_xor(32); row written once (coalesced 512 B).
// ---------------------------------------------------------------------------
template <typename T>
__global__ __launch_bounds__(512, 4) void k_rowedge(
    const int* __restrict__ csr_col, const int* __restrict__ row_start,
    const T* __restrict__ pack, const unsigned char* __restrict__ group8,
    const float* __restrict__ Sg, float* __restrict__ outacc,
    double* __restrict__ head_sum, int N) {
    __shared__ float4 sg4[64 * 32];   // Sg as float4[group][chunk], 32 KB
    __shared__ float hsum[4];

    const int tid = threadIdx.x;
    for (int i = tid; i < 64 * 32; i += 512) sg4[i] = ((const float4*)Sg)[i];
    if (tid < 4) hsum[tid] = 0.f;
    __syncthreads();

    const int wid = tid >> 6;      // wave 0..7 -> row
    const int l = tid & 63;
    const int half = l >> 5;       // edge-stream 0 or 1
    const int hl = l & 31;         // float4 chunk (channels 4hl..4hl+3)
    const int row = blockIdx.x * 8 + wid;

    const float inv_scale = 0.05892556509887896f;  // 1/(3*sqrt(32))
    float lsum = 0.f;

    if (row < N) {
        const T* rp = pack + (size_t)row * 384;
        float4 q = ld4(rp, hl);
        float4 sr = sg4[(int)group8[row] * 32 + hl];
        float4 qs = make_float4(q.x + sr.x, q.y + sr.y, q.z + sr.z, q.w + sr.w);
        float4 acc = make_float4(0.f, 0.f, 0.f, 0.f);

        const int beg = row_start[row];
        const int end = row_start[row + 1];
        // this half handles edges beg+half, beg+half+2, ... ; unroll x2
        for (int i = beg + half; i < end; i += 4) {
            const int iB = i + 2;
            const bool vB = iB < end;
            int colA = csr_col[i];
            int colB = vB ? csr_col[iB] : colA;   // safe duplicate; pB forced 0
            const T* cpA = pack + (size_t)colA * 384;
            const T* cpB = pack + (size_t)colB * 384;
            float4 kkA = ld4(cpA + 128, hl);
            float4 vvA = ld4(cpA + 256, hl);
            float4 kkB = ld4(cpB + 128, hl);
            float4 vvB = ld4(cpB + 256, hl);
            float4 scA = sg4[(int)group8[colA] * 32 + hl];
            float4 scB = sg4[(int)group8[colB] * 32 + hl];

            float tA = qs.x * kkA.x + qs.y * kkA.y + qs.z * kkA.z + qs.w * kkA.w
                     + q.x * scA.x + q.y * scA.y + q.z * scA.z + q.w * scA.w;
            float tB = qs.x * kkB.x + qs.y * kkB.y + qs.z * kkB.z + qs.w * kkB.w
                     + q.x * scB.x + q.y * scB.y + q.z * scB.z + q.w * scB.w;
            tA += __shfl_xor(tA, 1);  tB += __shfl_xor(tB, 1);
            tA += __shfl_xor(tA, 2);  tB += __shfl_xor(tB, 2);
            tA += __shfl_xor(tA, 4);  tB += __shfl_xor(tB, 4);

            float aA = tA * inv_scale;
            aA = (aA >= 0.f) ? aA : 0.2f * aA;    // leaky_relu(0.2)
            float aB = tB * inv_scale;
            aB = (aB >= 0.f) ? aB : 0.2f * aB;
            float pA = expf(aA);
            float pB = vB ? expf(aB) : 0.f;

            if ((hl & 7) == 0) lsum += pA + pB;
            acc.x += pA * vvA.x + pB * vvB.x;
            acc.y += pA * vvA.y + pB * vvB.y;
            acc.z += pA * vvA.z + pB * vvB.z;
            acc.w += pA * vvA.w + pB * vvB.w;
        }

        // combine the two halves' accumulators (lanes l and l^32)
        acc.x += __shfl_xor(acc.x, 32);
        acc.y += __shfl_xor(acc.y, 32);
        acc.z += __shfl_xor(acc.z, 32);
        acc.w += __shfl_xor(acc.w, 32);
        if (half == 0)
            ((float4*)(outacc + (size_t)row * 128))[hl] = acc;
    }

    if ((l & 7) == 0) atomicAdd(&hsum[(l & 31) >> 3], lsum);
    __syncthreads();
    if (tid < 4) atomicAdd(&head_sum[tid], (double)hsum[tid]);
}

// ---------------------------------------------------------------------------
// Kernel 4: out = (outacc * (1/head_sum)) @ Wo + bo + x
// outacc aliases d_out; each block stages only its own 32 rows -> safe.
// ---------------------------------------------------------------------------
__global__ __launch_bounds__(256) void k_out(
    const float* __restrict__ outacc, const double* __restrict__ head_sum,
    const float* __restrict__ Wo, const float* __restrict__ bo,
    const float* __restrict__ x, float* __restrict__ out, int N) {
    __shared__ float4 ys[32][32];

    const int row0 = blockIdx.x * 32;
    const int tid = threadIdx.x;

    float inv[4];
    #pragma unroll
    for (int hh = 0; hh < 4; ++hh) inv[hh] = (float)(1.0 / head_sum[hh]);

    for (int i = tid; i < 32 * 32; i += 256) {
        int r = i >> 5, k4 = i & 31;
        int row = row0 + r;
        float4 v = make_float4(0.f, 0.f, 0.f, 0.f);
        if (row < N) v = ((const float4*)outacc)[(size_t)row * 32 + k4];
        float s = inv[k4 >> 3];
        v.x *= s; v.y *= s; v.z *= s; v.w *= s;
        ys[r][k4] = v;
    }
    __syncthreads();

    const int o = tid & 127;
    const int half_ = tid >> 7;
    float acc[16];
    #pragma unroll
    for (int r = 0; r < 16; ++r) acc[r] = 0.f;
    for (int k4 = 0; k4 < 32; ++k4) {
        float w0 = Wo[(k4 * 4 + 0) * 128 + o];
        float w1 = Wo[(k4 * 4 + 1) * 128 + o];
        float w2 = Wo[(k4 * 4 + 2) * 128 + o];
        float w3 = Wo[(k4 * 4 + 3) * 128 + o];
        #pragma unroll
        for (int r = 0; r < 16; ++r) {
            float4 yv = ys[half_ * 16 + r][k4];
            acc[r] += yv.x * w0 + yv.y * w1 + yv.z * w2 + yv.w * w3;
        }
    }
    float b = bo[o];
    #pragma unroll
    for (int r = 0; r < 16; ++r) {
        int row = row0 + half_ * 16 + r;
        if (row < N)
            out[(size_t)row * 128 + o] = acc[r] + b + x[(size_t)row * 128 + o];
    }
}

// ---------------------------------------------------------------------------
extern "C" void kernel_launch(void* const* d_in, const int* in_sizes, int n_in,
                              void* d_out, int out_size, void* d_ws, size_t ws_size,
                              hipStream_t stream) {
    const float* x     = (const float*)d_in[0];
    const int*   eidx  = (const int*)d_in[1];
    const float* sent  = (const float*)d_in[2];
    const int*   batch = (const int*)d_in[3];
    const float* Wq = (const float*)d_in[4];
    const float* bq = (const float*)d_in[5];
    const float* Wk = (const float*)d_in[6];
    const float* bk = (const float*)d_in[7];
    const float* Wv = (const float*)d_in[8];
    const float* bv = (const float*)d_in[9];
    const float* Ws = (const float*)d_in[10];
    const float* bs = (const float*)d_in[11];
    const float* Wo = (const float*)d_in[12];
    const float* bo = (const float*)d_in[13];

    const int N = in_sizes[0] / 128;   // 50000
    const int E = in_sizes[1] / 2;     // 800000

    // ---- workspace layout (256B-aligned slots) ----
    char* ws = (char*)d_ws;
    size_t off = 0;
    auto alloc = [&](size_t bytes) {
        char* p = ws + off;
        off += (bytes + 255) & ~(size_t)255;
        return p;
    };
    float*  Sg        = (float*)alloc(64 * 128 * sizeof(float));   // 32 KB
    double* head_sum  = (double*)alloc(4 * sizeof(double));
    unsigned char* group8 = (unsigned char*)alloc((size_t)N);
    int* counts    = (int*)alloc((size_t)N * sizeof(int));
    int* row_start = (int*)alloc(((size_t)N + 1) * sizeof(int));
    int* cursor    = (int*)alloc((size_t)N * sizeof(int));
    int* csr_col   = (int*)alloc((size_t)E * sizeof(int));
    size_t pack_off = off;
    size_t need_f32 = pack_off + (size_t)N * 384 * sizeof(float);
    bool use_f32 = (ws_size >= need_f32);

    float* outacc = (float*)d_out;   // aliased; k_rowedge writes every row once

    hipMemsetAsync(counts, 0, (size_t)N * sizeof(int), stream);
    hipMemsetAsync(head_sum, 0, 4 * sizeof(double), stream);

    k_sgemm<<<64, 128, 0, stream>>>(sent, Ws, bs, Sg);

    const int eb = (E + 255) / 256;
    k_hist<<<eb, 256, 0, stream>>>(eidx, counts, E);
    k_scan<<<1, 1024, 0, stream>>>(counts, row_start, cursor, N);
    k_scatter<<<eb, 256, 0, stream>>>(eidx, cursor, csr_col, E);

    const int qkv_blocks = (N + 31) / 32;
    const int row_blocks = (N + 7) / 8;
    if (use_f32) {
        float* pack = (float*)(ws + pack_off);
        k_qkv<float><<<qkv_blocks, 256, 0, stream>>>(x, batch, Wq, bq, Wk, bk,
                                                     Wv, bv, pack, group8, N);
        k_rowedge<float><<<row_blocks, 512, 0, stream>>>(csr_col, row_start, pack,
                                                         group8, Sg, outacc,
                                                         head_sum, N);
    } else {
        __half* pack = (__half*)(ws + pack_off);
        k_qkv<__half><<<qkv_blocks, 256, 0, stream>>>(x, batch, Wq, bq, Wk, bk,
                                                      Wv, bv, pack, group8, N);
        k_rowedge<__half><<<row_blocks, 512, 0, stream>>>(csr_col, row_start, pack,
                                                          group8, Sg, outacc,
                                                          head_sum, N);
    }

    k_out<<<qkv_blocks, 256, 0, stream>>>(outacc, head_sum, Wo, bo, x,
                                          (float*)d_out, N);
}

// Round 9
// 534.536 us; speedup vs baseline: 3.1723x; 1.1727x over previous
//
#include <hip/hip_runtime.h>
#include <hip/hip_fp16.h>
#include <hip/hip_bf16.h>

// Problem constants: N=50000, E=800000, IN=OUT=128, H=4, C=32, TOKEN=768,
// OPTION=4, NGRAPH=256 -> 64 sentence groups.
//
// alpha*3*sqrt(C) = (Q_i+S_i).K_j + Q_i.S_j ; S_i = Sg[batch[i]>>2] (64 rows).
// Global softmax over all edges per head; |alpha| << 1 so no max pass needed:
// scatter unnormalized p*V, track per-head sum(p), normalize in final GEMM.
//
// Round-9 change (k_qkv only): replace scalar fp32 projection GEMM with
// split-bf16 MFMA (x=xh+xl, W=Wh+Wl; keep xh*Wh+xh*Wl+xl*Wh -> rel err ~1e-5).
// W is pre-swizzled into per-lane fragment order by k_wsplit so A and B use
// the SAME k-placement (any consistent permutation is valid since CDNA A/B
// layouts are k-symmetric). C/D layout: col=lane&15, row=(lane>>4)*4+reg.

typedef __attribute__((ext_vector_type(8))) short bfx8;   // 8 bf16 = 4 VGPR
typedef __attribute__((ext_vector_type(4))) float f32x4;  // MFMA C/D

__device__ __forceinline__ unsigned short f2bf(float f) {
    union { float f; unsigned int u; } v; v.f = f;
    unsigned int r = v.u + 0x7fffu + ((v.u >> 16) & 1u);  // RNE
    return (unsigned short)(r >> 16);
}
__device__ __forceinline__ float bf2f(unsigned short u) {
    union { unsigned int u; float f; } v; v.u = ((unsigned int)u) << 16;
    return v.f;
}

// ---------- pack element helpers (fp32 or fp16 scratch) ----------
__device__ __forceinline__ float4 ld4(const float* p, int i) {
    return ((const float4*)p)[i];
}
__device__ __forceinline__ float4 ld4(const __half* p, int i) {
    __half2 h01 = ((const __half2*)p)[2 * i];
    __half2 h23 = ((const __half2*)p)[2 * i + 1];
    float2 a = __half22float2(h01);
    float2 b = __half22float2(h23);
    return make_float4(a.x, a.y, b.x, b.y);
}
__device__ __forceinline__ void st1(float* p, float v) { *p = v; }
__device__ __forceinline__ void st1(__half* p, float v) { *p = __float2half_rn(v); }

// ---------------------------------------------------------------------------
// Kernel 1: Sg[64][128] = sentence_embeddings[64][768] @ Ws + bs
// ---------------------------------------------------------------------------
__global__ void k_sgemm(const float* __restrict__ sent, const float* __restrict__ Ws,
                        const float* __restrict__ bs, float* __restrict__ Sg) {
    int g = blockIdx.x;      // 0..63
    int o = threadIdx.x;     // 0..127
    const float* s = sent + g * 768;
    float acc = 0.f;
    #pragma unroll 8
    for (int k = 0; k < 768; ++k) acc += s[k] * Ws[k * 128 + o];
    Sg[g * 128 + o] = acc + bs[o];
}

// ---------------------------------------------------------------------------
// k_wsplit: Wcat = [Wq|Wk|Wv] (128k x 384n) -> bf16 hi/lo in MFMA fragment
// order: wfrag[split][ngrp*4+kstep][lane][8], elem e of lane l is
// (n = ngrp*16 + (l&15), k = kstep*32 + 8*(l>>4) + e). Also bcat[384].
// ---------------------------------------------------------------------------
__global__ __launch_bounds__(256) void k_wsplit(
    const float* __restrict__ Wq, const float* __restrict__ Wk,
    const float* __restrict__ Wv, const float* __restrict__ bq,
    const float* __restrict__ bk, const float* __restrict__ bv,
    unsigned short* __restrict__ wfrag, float* __restrict__ bcat) {
    int gid = blockIdx.x * 256 + threadIdx.x;   // 0..6143
    if (gid < 384)
        bcat[gid] = (gid < 128) ? bq[gid] : (gid < 256) ? bk[gid - 128] : bv[gid - 256];
    int l = gid & 63;
    int fk = gid >> 6;            // 0..95 = ngrp*4 + kstep
    int ks = fk & 3, ng = fk >> 2;
    int n = ng * 16 + (l & 15);
    const float* W = (n < 128) ? Wq : (n < 256) ? Wk : Wv;
    int col = n & 127;
    int kbase = ks * 32 + (l >> 4) * 8;
    bfx8 hv, lv;
    #pragma unroll
    for (int e = 0; e < 8; ++e) {
        float v = W[(size_t)(kbase + e) * 128 + col];
        unsigned short h = f2bf(v);
        hv[e] = (short)h;
        lv[e] = (short)f2bf(v - bf2f(h));
    }
    ((bfx8*)wfrag)[fk * 64 + l] = hv;               // split 0 (hi)
    ((bfx8*)wfrag)[6144 + fk * 64 + l] = lv;        // split 1 (lo)
}

// ---------------------------------------------------------------------------
// k_qkv_mfma: pack[i] = {Q,K,V}(384) via split-bf16 MFMA.
// Block: 256 thr = 4 waves; 32 rows x 384 cols. Wave w -> cols [96w, 96w+96).
// x tile staged as bf16 hi/lo in LDS, 16B units XOR-swizzled (u ^= row&7).
// A frag: lane l -> row (l&15)+16*m, k-unit kstep*4+(l>>4) (one b128 read).
// ---------------------------------------------------------------------------
__global__ __launch_bounds__(256) void k_qkv_mfma(
    const float* __restrict__ x, const int* __restrict__ batch,
    const unsigned short* __restrict__ wfrag, const float* __restrict__ bcat,
    float* __restrict__ pack, unsigned char* __restrict__ group8, int N) {
    __shared__ __align__(16) unsigned short hi_lds[32 * 128];  // 8 KB
    __shared__ __align__(16) unsigned short lo_lds[32 * 128];  // 8 KB

    const int tid = threadIdx.x;
    const int row0 = blockIdx.x * 32;

    // stage x -> bf16 hi/lo (512 tasks: row r, 16B-unit u)
    const float4* x4 = (const float4*)x;
    #pragma unroll
    for (int t = tid; t < 512; t += 256) {
        int r = t >> 4, u = t & 15;
        int row = row0 + r;
        float4 a = make_float4(0.f, 0.f, 0.f, 0.f), b = a;
        if (row < N) {
            a = x4[(size_t)row * 32 + u * 2];
            b = x4[(size_t)row * 32 + u * 2 + 1];
        }
        float v[8] = {a.x, a.y, a.z, a.w, b.x, b.y, b.z, b.w};
        bfx8 hv, lv;
        #pragma unroll
        for (int e = 0; e < 8; ++e) {
            unsigned short h = f2bf(v[e]);
            hv[e] = (short)h;
            lv[e] = (short)f2bf(v[e] - bf2f(h));
        }
        int su = r * 16 + (u ^ (r & 7));
        ((bfx8*)hi_lds)[su] = hv;
        ((bfx8*)lo_lds)[su] = lv;
    }
    if (tid < 32) {
        int row = row0 + tid;
        if (row < N) group8[row] = (unsigned char)(batch[row] >> 2);
    }
    __syncthreads();

    const int w = tid >> 6;      // wave -> col group [96w, 96w+96)
    const int l = tid & 63;
    const int l15 = l & 15, lh = l >> 4;

    f32x4 zero = {0.f, 0.f, 0.f, 0.f};
    f32x4 acc[2][6];
    #pragma unroll
    for (int m = 0; m < 2; ++m)
        #pragma unroll
        for (int n = 0; n < 6; ++n) acc[m][n] = zero;

    const bfx8* wf = (const bfx8*)wfrag;
    const bfx8* hi8 = (const bfx8*)hi_lds;
    const bfx8* lo8 = (const bfx8*)lo_lds;

    #pragma unroll
    for (int ks = 0; ks < 4; ++ks) {
        bfx8 bh[6], bl[6];
        #pragma unroll
        for (int n = 0; n < 6; ++n) {
            int fk = (w * 6 + n) * 4 + ks;
            bh[n] = wf[fk * 64 + l];
            bl[n] = wf[6144 + fk * 64 + l];
        }
        bfx8 ah[2], al[2];
        #pragma unroll
        for (int m = 0; m < 2; ++m) {
            int r = m * 16 + l15;
            int su = r * 16 + ((ks * 4 + lh) ^ (r & 7));
            ah[m] = hi8[su];
            al[m] = lo8[su];
        }
        #pragma unroll
        for (int m = 0; m < 2; ++m)
            #pragma unroll
            for (int n = 0; n < 6; ++n) {
                acc[m][n] = __builtin_amdgcn_mfma_f32_16x16x32_bf16(ah[m], bh[n], acc[m][n], 0, 0, 0);
                acc[m][n] = __builtin_amdgcn_mfma_f32_16x16x32_bf16(ah[m], bl[n], acc[m][n], 0, 0, 0);
                acc[m][n] = __builtin_amdgcn_mfma_f32_16x16x32_bf16(al[m], bh[n], acc[m][n], 0, 0, 0);
            }
    }

    // epilogue: D[i][j]: i=(l>>4)*4+reg (+16m), j=l&15 (+16n); add bias, store
    #pragma unroll
    for (int n = 0; n < 6; ++n) {
        int colg = w * 96 + n * 16 + l15;
        float bias = bcat[colg];
        #pragma unroll
        for (int m = 0; m < 2; ++m) {
            int rbase = row0 + m * 16 + lh * 4;
            #pragma unroll
            for (int j = 0; j < 4; ++j) {
                int rr = rbase + j;
                if (rr < N) pack[(size_t)rr * 384 + colg] = acc[m][n][j] + bias;
            }
        }
    }
}

// ---------------------------------------------------------------------------
// Fallback scalar QKV (used only if ws can't fit the fp32 pack)
// ---------------------------------------------------------------------------
template <typename T>
__global__ __launch_bounds__(256) void k_qkv(
    const float* __restrict__ x, const int* __restrict__ batch,
    const float* __restrict__ Wq, const float* __restrict__ bq,
    const float* __restrict__ Wk, const float* __restrict__ bk,
    const float* __restrict__ Wv, const float* __restrict__ bv,
    T* __restrict__ pack, unsigned char* __restrict__ group8, int N) {
    __shared__ float4 xs[32][32];

    const int row0 = blockIdx.x * 32;
    const int tid = threadIdx.x;

    for (int i = tid; i < 32 * 32; i += 256) {
        int r = i >> 5, k4 = i & 31;
        int row = row0 + r;
        float4 v = make_float4(0.f, 0.f, 0.f, 0.f);
        if (row < N) v = ((const float4*)x)[(size_t)row * 32 + k4];
        xs[r][k4] = v;
    }
    if (tid < 32) {
        int row = row0 + tid;
        if (row < N) group8[row] = (unsigned char)(batch[row] >> 2);
    }
    __syncthreads();

    const int o = tid & 127;
    const int half_ = tid >> 7;

    const float* Wm[3] = {Wq, Wk, Wv};
    const float* bm[3] = {bq, bk, bv};

    #pragma unroll
    for (int m = 0; m < 3; ++m) {
        const float* __restrict__ W = Wm[m];
        float acc[16];
        #pragma unroll
        for (int r = 0; r < 16; ++r) acc[r] = 0.f;
        for (int k4 = 0; k4 < 32; ++k4) {
            float w0 = W[(k4 * 4 + 0) * 128 + o];
            float w1 = W[(k4 * 4 + 1) * 128 + o];
            float w2 = W[(k4 * 4 + 2) * 128 + o];
            float w3 = W[(k4 * 4 + 3) * 128 + o];
            #pragma unroll
            for (int r = 0; r < 16; ++r) {
                float4 xv = xs[half_ * 16 + r][k4];
                acc[r] += xv.x * w0 + xv.y * w1 + xv.z * w2 + xv.w * w3;
            }
        }
        float b = bm[m][o];
        #pragma unroll
        for (int r = 0; r < 16; ++r) {
            int row = row0 + half_ * 16 + r;
            if (row >= N) continue;
            st1(&pack[(size_t)row * 384 + m * 128 + o], acc[r] + b);
        }
    }
}

// ---------------------------------------------------------------------------
// CSR build: histogram -> exclusive scan -> scatter cols by destination row
// ---------------------------------------------------------------------------
__global__ __launch_bounds__(256) void k_hist(const int* __restrict__ eidx,
                                              int* __restrict__ counts, int E) {
    int e = blockIdx.x * 256 + threadIdx.x;
    if (e < E) atomicAdd(&counts[eidx[e]], 1);
}

__global__ __launch_bounds__(1024) void k_scan(const int* __restrict__ counts,
                                               int* __restrict__ row_start,
                                               int* __restrict__ cursor, int N) {
    __shared__ int part[1024];
    const int tid = threadIdx.x;
    const int chunk = (N + 1023) >> 10;
    const int lo = tid * chunk;
    const int hi = min(lo + chunk, N);
    int s = 0;
    for (int i = lo; i < hi; ++i) s += counts[i];
    part[tid] = s;
    __syncthreads();
    for (int d = 1; d < 1024; d <<= 1) {
        int v = 0;
        if (tid >= d) v = part[tid - d];
        __syncthreads();
        if (tid >= d) part[tid] += v;
        __syncthreads();
    }
    int run = (tid == 0) ? 0 : part[tid - 1];
    for (int i = lo; i < hi; ++i) {
        row_start[i] = run;
        cursor[i] = run;
        run += counts[i];
    }
    if (tid == 0) row_start[N] = part[1023];
}

__global__ __launch_bounds__(256) void k_scatter(const int* __restrict__ eidx,
                                                 int* __restrict__ cursor,
                                                 int* __restrict__ csr_col, int E) {
    int e = blockIdx.x * 256 + threadIdx.x;
    if (e < E) {
        int row = eidx[e];
        int col = eidx[E + e];
        int pos = atomicAdd(&cursor[row], 1);
        csr_col[pos] = col;
    }
}

// ---------------------------------------------------------------------------
// k_rowedge: one wave per destination row; two 32-lane halves each own an
// interleaved stream of the row's edges, unrolled x2 (4 gather chains).
// ---------------------------------------------------------------------------
template <typename T>
__global__ __launch_bounds__(512, 4) void k_rowedge(
    const int* __restrict__ csr_col, const int* __restrict__ row_start,
    const T* __restrict__ pack, const unsigned char* __restrict__ group8,
    const float* __restrict__ Sg, float* __restrict__ outacc,
    double* __restrict__ head_sum, int N) {
    __shared__ float4 sg4[64 * 32];   // Sg as float4[group][chunk], 32 KB
    __shared__ float hsum[4];

    const int tid = threadIdx.x;
    for (int i = tid; i < 64 * 32; i += 512) sg4[i] = ((const float4*)Sg)[i];
    if (tid < 4) hsum[tid] = 0.f;
    __syncthreads();

    const int wid = tid >> 6;      // wave 0..7 -> row
    const int l = tid & 63;
    const int half = l >> 5;       // edge-stream 0 or 1
    const int hl = l & 31;         // float4 chunk (channels 4hl..4hl+3)
    const int row = blockIdx.x * 8 + wid;

    const float inv_scale = 0.05892556509887896f;  // 1/(3*sqrt(32))
    float lsum = 0.f;

    if (row < N) {
        const T* rp = pack + (size_t)row * 384;
        float4 q = ld4(rp, hl);
        float4 sr = sg4[(int)group8[row] * 32 + hl];
        float4 qs = make_float4(q.x + sr.x, q.y + sr.y, q.z + sr.z, q.w + sr.w);
        float4 acc = make_float4(0.f, 0.f, 0.f, 0.f);

        const int beg = row_start[row];
        const int end = row_start[row + 1];
        for (int i = beg + half; i < end; i += 4) {
            const int iB = i + 2;
            const bool vB = iB < end;
            int colA = csr_col[i];
            int colB = vB ? csr_col[iB] : colA;
            const T* cpA = pack + (size_t)colA * 384;
            const T* cpB = pack + (size_t)colB * 384;
            float4 kkA = ld4(cpA + 128, hl);
            float4 vvA = ld4(cpA + 256, hl);
            float4 kkB = ld4(cpB + 128, hl);
            float4 vvB = ld4(cpB + 256, hl);
            float4 scA = sg4[(int)group8[colA] * 32 + hl];
            float4 scB = sg4[(int)group8[colB] * 32 + hl];

            float tA = qs.x * kkA.x + qs.y * kkA.y + qs.z * kkA.z + qs.w * kkA.w
                     + q.x * scA.x + q.y * scA.y + q.z * scA.z + q.w * scA.w;
            float tB = qs.x * kkB.x + qs.y * kkB.y + qs.z * kkB.z + qs.w * kkB.w
                     + q.x * scB.x + q.y * scB.y + q.z * scB.z + q.w * scB.w;
            tA += __shfl_xor(tA, 1);  tB += __shfl_xor(tB, 1);
            tA += __shfl_xor(tA, 2);  tB += __shfl_xor(tB, 2);
            tA += __shfl_xor(tA, 4);  tB += __shfl_xor(tB, 4);

            float aA = tA * inv_scale;
            aA = (aA >= 0.f) ? aA : 0.2f * aA;
            float aB = tB * inv_scale;
            aB = (aB >= 0.f) ? aB : 0.2f * aB;
            float pA = expf(aA);
            float pB = vB ? expf(aB) : 0.f;

            if ((hl & 7) == 0) lsum += pA + pB;
            acc.x += pA * vvA.x + pB * vvB.x;
            acc.y += pA * vvA.y + pB * vvB.y;
            acc.z += pA * vvA.z + pB * vvB.z;
            acc.w += pA * vvA.w + pB * vvB.w;
        }

        acc.x += __shfl_xor(acc.x, 32);
        acc.y += __shfl_xor(acc.y, 32);
        acc.z += __shfl_xor(acc.z, 32);
        acc.w += __shfl_xor(acc.w, 32);
        if (half == 0)
            ((float4*)(outacc + (size_t)row * 128))[hl] = acc;
    }

    if ((l & 7) == 0) atomicAdd(&hsum[(l & 31) >> 3], lsum);
    __syncthreads();
    if (tid < 4) atomicAdd(&head_sum[tid], (double)hsum[tid]);
}

// ---------------------------------------------------------------------------
// Kernel 4: out = (outacc * (1/head_sum)) @ Wo + bo + x
// ---------------------------------------------------------------------------
__global__ __launch_bounds__(256) void k_out(
    const float* __restrict__ outacc, const double* __restrict__ head_sum,
    const float* __restrict__ Wo, const float* __restrict__ bo,
    const float* __restrict__ x, float* __restrict__ out, int N) {
    __shared__ float4 ys[32][32];

    const int row0 = blockIdx.x * 32;
    const int tid = threadIdx.x;

    float inv[4];
    #pragma unroll
    for (int hh = 0; hh < 4; ++hh) inv[hh] = (float)(1.0 / head_sum[hh]);

    for (int i = tid; i < 32 * 32; i += 256) {
        int r = i >> 5, k4 = i & 31;
        int row = row0 + r;
        float4 v = make_float4(0.f, 0.f, 0.f, 0.f);
        if (row < N) v = ((const float4*)outacc)[(size_t)row * 32 + k4];
        float s = inv[k4 >> 3];
        v.x *= s; v.y *= s; v.z *= s; v.w *= s;
        ys[r][k4] = v;
    }
    __syncthreads();

    const int o = tid & 127;
    const int half_ = tid >> 7;
    float acc[16];
    #pragma unroll
    for (int r = 0; r < 16; ++r) acc[r] = 0.f;
    for (int k4 = 0; k4 < 32; ++k4) {
        float w0 = Wo[(k4 * 4 + 0) * 128 + o];
        float w1 = Wo[(k4 * 4 + 1) * 128 + o];
        float w2 = Wo[(k4 * 4 + 2) * 128 + o];
        float w3 = Wo[(k4 * 4 + 3) * 128 + o];
        #pragma unroll
        for (int r = 0; r < 16; ++r) {
            float4 yv = ys[half_ * 16 + r][k4];
            acc[r] += yv.x * w0 + yv.y * w1 + yv.z * w2 + yv.w * w3;
        }
    }
    float b = bo[o];
    #pragma unroll
    for (int r = 0; r < 16; ++r) {
        int row = row0 + half_ * 16 + r;
        if (row < N)
            out[(size_t)row * 128 + o] = acc[r] + b + x[(size_t)row * 128 + o];
    }
}

// ---------------------------------------------------------------------------
extern "C" void kernel_launch(void* const* d_in, const int* in_sizes, int n_in,
                              void* d_out, int out_size, void* d_ws, size_t ws_size,
                              hipStream_t stream) {
    const float* x     = (const float*)d_in[0];
    const int*   eidx  = (const int*)d_in[1];
    const float* sent  = (const float*)d_in[2];
    const int*   batch = (const int*)d_in[3];
    const float* Wq = (const float*)d_in[4];
    const float* bq = (const float*)d_in[5];
    const float* Wk = (const float*)d_in[6];
    const float* bk = (const float*)d_in[7];
    const float* Wv = (const float*)d_in[8];
    const float* bv = (const float*)d_in[9];
    const float* Ws = (const float*)d_in[10];
    const float* bs = (const float*)d_in[11];
    const float* Wo = (const float*)d_in[12];
    const float* bo = (const float*)d_in[13];

    const int N = in_sizes[0] / 128;   // 50000
    const int E = in_sizes[1] / 2;     // 800000

    // ---- workspace layout (256B-aligned slots) ----
    char* ws = (char*)d_ws;
    size_t off = 0;
    auto alloc = [&](size_t bytes) {
        char* p = ws + off;
        off += (bytes + 255) & ~(size_t)255;
        return p;
    };
    float*  Sg        = (float*)alloc(64 * 128 * sizeof(float));   // 32 KB
    double* head_sum  = (double*)alloc(4 * sizeof(double));
    unsigned char* group8 = (unsigned char*)alloc((size_t)N);
    int* counts    = (int*)alloc((size_t)N * sizeof(int));
    int* row_start = (int*)alloc(((size_t)N + 1) * sizeof(int));
    int* cursor    = (int*)alloc((size_t)N * sizeof(int));
    int* csr_col   = (int*)alloc((size_t)E * sizeof(int));
    unsigned short* wfrag = (unsigned short*)alloc(2 * 96 * 64 * 8 * sizeof(unsigned short)); // 192 KB
    float* bcat    = (float*)alloc(384 * sizeof(float));
    size_t pack_off = off;
    size_t need_f32 = pack_off + (size_t)N * 384 * sizeof(float);
    bool use_f32 = (ws_size >= need_f32);

    float* outacc = (float*)d_out;   // aliased; k_rowedge writes every row once

    hipMemsetAsync(counts, 0, (size_t)N * sizeof(int), stream);
    hipMemsetAsync(head_sum, 0, 4 * sizeof(double), stream);

    k_sgemm<<<64, 128, 0, stream>>>(sent, Ws, bs, Sg);

    const int eb = (E + 255) / 256;
    k_hist<<<eb, 256, 0, stream>>>(eidx, counts, E);
    k_scan<<<1, 1024, 0, stream>>>(counts, row_start, cursor, N);
    k_scatter<<<eb, 256, 0, stream>>>(eidx, cursor, csr_col, E);

    const int qkv_blocks = (N + 31) / 32;
    const int row_blocks = (N + 7) / 8;
    if (use_f32) {
        float* pack = (float*)(ws + pack_off);
        k_wsplit<<<24, 256, 0, stream>>>(Wq, Wk, Wv, bq, bk, bv, wfrag, bcat);
        k_qkv_mfma<<<qkv_blocks, 256, 0, stream>>>(x, batch, wfrag, bcat,
                                                   pack, group8, N);
        k_rowedge<float><<<row_blocks, 512, 0, stream>>>(csr_col, row_start, pack,
                                                         group8, Sg, outacc,
                                                         head_sum, N);
    } else {
        __half* pack = (__half*)(ws + pack_off);
        k_qkv<__half><<<qkv_blocks, 256, 0, stream>>>(x, batch, Wq, bq, Wk, bk,
                                                      Wv, bv, pack, group8, N);
        k_rowedge<__half><<<row_blocks, 512, 0, stream>>>(csr_col, row_start, pack,
                                                          group8, Sg, outacc,
                                                          head_sum, N);
    }

    k_out<<<qkv_blocks, 256, 0, stream>>>(outacc, head_sum, Wo, bo, x,
                                          (float*)d_out, N);
}

// Round 10
// 467.664 us; speedup vs baseline: 3.6259x; 1.1430x over previous
//
#include <hip/hip_runtime.h>
#include <hip/hip_fp16.h>
#include <hip/hip_bf16.h>

// N=50000, E=800000, IN=OUT=128, H=4, C=32, TOKEN=768, OPTION=4, NGRAPH=256
// -> 64 sentence groups.
//
// alpha*3*sqrt(C) = (Q_i+S_i).K_j + Q_i.S_j ; S_i = Sg[batch[i]>>2] (64 rows).
// Global softmax, |alpha| << 1 -> no max pass: accumulate unnormalized p*V per
// row (CSR, one wave/row), track per-head sum(p), normalize in final GEMM.
//
// Round-10: fp16 pack (halves rowedge gather bytes + qkv write bytes),
// k_out via split-bf16 MFMA, prep kernels fused into one dispatch.

typedef __attribute__((ext_vector_type(8))) short bfx8;   // 8 bf16 = 4 VGPR
typedef __attribute__((ext_vector_type(4))) float f32x4;  // MFMA C/D

__device__ __forceinline__ unsigned short f2bf(float f) {
    union { float f; unsigned int u; } v; v.f = f;
    unsigned int r = v.u + 0x7fffu + ((v.u >> 16) & 1u);  // RNE
    return (unsigned short)(r >> 16);
}
__device__ __forceinline__ float bf2f(unsigned short u) {
    union { unsigned int u; float f; } v; v.u = ((unsigned int)u) << 16;
    return v.f;
}
// one 8B load = 4 halves -> float4
__device__ __forceinline__ float4 ld4h(const __half* p) {
    float2 raw = *(const float2*)p;
    union { float2 f; __half2 h[2]; } u; u.f = raw;
    float2 a = __half22float2(u.h[0]);
    float2 b = __half22float2(u.h[1]);
    return make_float4(a.x, a.y, b.x, b.y);
}

// ---------------------------------------------------------------------------
// k_prep (fused): blocks 0..31 -> Sg GEMM (2 groups/block);
// blocks 32..63 -> weight split/swizzle (QKV + Wo -> bf16 hi/lo fragments);
// blocks 64..  -> edge histogram.
// wfrag layout (bfx8 units): hi at [fk*64+l], lo at [8192 + fk*64+l];
// fk 0..95 = QKV (n = (fk>>2)*16 + (l&15) in 0..383), fk 96..127 = Wo.
// elem e of lane l: k = (fk&3)*32 + (l>>4)*8 + e.  bcat = [bq|bk|bv|bo] (512).
// ---------------------------------------------------------------------------
__global__ __launch_bounds__(256) void k_prep(
    const float* __restrict__ sent, const float* __restrict__ Ws,
    const float* __restrict__ bs, float* __restrict__ Sg,
    const float* __restrict__ Wq, const float* __restrict__ Wk,
    const float* __restrict__ Wv, const float* __restrict__ Wo,
    const float* __restrict__ bq, const float* __restrict__ bk,
    const float* __restrict__ bv, const float* __restrict__ bo,
    unsigned short* __restrict__ wfrag, float* __restrict__ bcat,
    const int* __restrict__ eidx, int* __restrict__ counts, int E) {
    const int b = blockIdx.x;
    const int tid = threadIdx.x;
    if (b < 32) {                       // --- Sg = sent @ Ws + bs ---
        int g = b * 2 + (tid >> 7);
        int o = tid & 127;
        const float* s = sent + g * 768;
        float acc = 0.f;
        #pragma unroll 8
        for (int k = 0; k < 768; ++k) acc += s[k] * Ws[k * 128 + o];
        Sg[g * 128 + o] = acc + bs[o];
    } else if (b < 64) {                // --- weight fragments ---
        int gid = (b - 32) * 256 + tid;     // 0..8191
        if (gid < 512)
            bcat[gid] = (gid < 128) ? bq[gid]
                      : (gid < 256) ? bk[gid - 128]
                      : (gid < 384) ? bv[gid - 256] : bo[gid - 384];
        int l = gid & 63;
        int fk = gid >> 6;                  // 0..127
        int ks = fk & 3;
        const float* W;
        int col;
        if (fk < 96) {
            int n = (fk >> 2) * 16 + (l & 15);          // 0..383
            W = (n < 128) ? Wq : (n < 256) ? Wk : Wv;
            col = n & 127;
        } else {
            col = ((fk - 96) >> 2) * 16 + (l & 15);     // 0..127
            W = Wo;
        }
        int kbase = ks * 32 + (l >> 4) * 8;
        bfx8 hv, lv;
        #pragma unroll
        for (int e = 0; e < 8; ++e) {
            float v = W[(size_t)(kbase + e) * 128 + col];
            unsigned short h = f2bf(v);
            hv[e] = (short)h;
            lv[e] = (short)f2bf(v - bf2f(h));
        }
        ((bfx8*)wfrag)[fk * 64 + l] = hv;
        ((bfx8*)wfrag)[8192 + fk * 64 + l] = lv;
    } else {                            // --- histogram ---
        int e = (b - 64) * 256 + tid;
        if (e < E) atomicAdd(&counts[eidx[e]], 1);
    }
}

// ---------------------------------------------------------------------------
// CSR: exclusive scan + scatter cols by destination row
// ---------------------------------------------------------------------------
__global__ __launch_bounds__(1024) void k_scan(const int* __restrict__ counts,
                                               int* __restrict__ row_start,
                                               int* __restrict__ cursor, int N) {
    __shared__ int part[1024];
    const int tid = threadIdx.x;
    const int chunk = (N + 1023) >> 10;
    const int lo = tid * chunk;
    const int hi = min(lo + chunk, N);
    int s = 0;
    for (int i = lo; i < hi; ++i) s += counts[i];
    part[tid] = s;
    __syncthreads();
    for (int d = 1; d < 1024; d <<= 1) {
        int v = 0;
        if (tid >= d) v = part[tid - d];
        __syncthreads();
        if (tid >= d) part[tid] += v;
        __syncthreads();
    }
    int run = (tid == 0) ? 0 : part[tid - 1];
    for (int i = lo; i < hi; ++i) {
        row_start[i] = run;
        cursor[i] = run;
        run += counts[i];
    }
    if (tid == 0) row_start[N] = part[1023];
}

__global__ __launch_bounds__(256) void k_scatter(const int* __restrict__ eidx,
                                                 int* __restrict__ cursor,
                                                 int* __restrict__ csr_col, int E) {
    int e = blockIdx.x * 256 + threadIdx.x;
    if (e < E) {
        int row = eidx[e];
        int col = eidx[E + e];
        int pos = atomicAdd(&cursor[row], 1);
        csr_col[pos] = col;
    }
}

// ---------------------------------------------------------------------------
// k_qkv_mfma: pack[i] = {Q,K,V}(384, fp16) via split-bf16 MFMA.
// 256 thr = 4 waves; 32 rows x 384 cols; wave w -> cols [96w, 96w+96).
// x staged as bf16 hi/lo in LDS, 16B units XOR-swizzled (u ^= r&7).
// C/D: col=lane&15, row=(lane>>4)*4+reg (verified m89).
// ---------------------------------------------------------------------------
__global__ __launch_bounds__(256) void k_qkv_mfma(
    const float* __restrict__ x, const int* __restrict__ batch,
    const unsigned short* __restrict__ wfrag, const float* __restrict__ bcat,
    __half* __restrict__ pack, unsigned char* __restrict__ group8, int N) {
    __shared__ __align__(16) unsigned short hi_lds[32 * 128];
    __shared__ __align__(16) unsigned short lo_lds[32 * 128];

    const int tid = threadIdx.x;
    const int row0 = blockIdx.x * 32;

    const float4* x4 = (const float4*)x;
    #pragma unroll
    for (int t = tid; t < 512; t += 256) {
        int r = t >> 4, u = t & 15;
        int row = row0 + r;
        float4 a = make_float4(0.f, 0.f, 0.f, 0.f), b = a;
        if (row < N) {
            a = x4[(size_t)row * 32 + u * 2];
            b = x4[(size_t)row * 32 + u * 2 + 1];
        }
        float v[8] = {a.x, a.y, a.z, a.w, b.x, b.y, b.z, b.w};
        bfx8 hv, lv;
        #pragma unroll
        for (int e = 0; e < 8; ++e) {
            unsigned short h = f2bf(v[e]);
            hv[e] = (short)h;
            lv[e] = (short)f2bf(v[e] - bf2f(h));
        }
        int su = r * 16 + (u ^ (r & 7));
        ((bfx8*)hi_lds)[su] = hv;
        ((bfx8*)lo_lds)[su] = lv;
    }
    if (tid < 32) {
        int row = row0 + tid;
        if (row < N) group8[row] = (unsigned char)(batch[row] >> 2);
    }
    __syncthreads();

    const int w = tid >> 6;
    const int l = tid & 63;
    const int l15 = l & 15, lh = l >> 4;

    f32x4 zero = {0.f, 0.f, 0.f, 0.f};
    f32x4 acc[2][6];
    #pragma unroll
    for (int m = 0; m < 2; ++m)
        #pragma unroll
        for (int n = 0; n < 6; ++n) acc[m][n] = zero;

    const bfx8* wf = (const bfx8*)wfrag;
    const bfx8* hi8 = (const bfx8*)hi_lds;
    const bfx8* lo8 = (const bfx8*)lo_lds;

    #pragma unroll
    for (int ks = 0; ks < 4; ++ks) {
        bfx8 bh[6], bl[6];
        #pragma unroll
        for (int n = 0; n < 6; ++n) {
            int fk = (w * 6 + n) * 4 + ks;
            bh[n] = wf[fk * 64 + l];
            bl[n] = wf[8192 + fk * 64 + l];
        }
        bfx8 ah[2], al[2];
        #pragma unroll
        for (int m = 0; m < 2; ++m) {
            int r = m * 16 + l15;
            int su = r * 16 + ((ks * 4 + lh) ^ (r & 7));
            ah[m] = hi8[su];
            al[m] = lo8[su];
        }
        #pragma unroll
        for (int m = 0; m < 2; ++m)
            #pragma unroll
            for (int n = 0; n < 6; ++n) {
                acc[m][n] = __builtin_amdgcn_mfma_f32_16x16x32_bf16(ah[m], bh[n], acc[m][n], 0, 0, 0);
                acc[m][n] = __builtin_amdgcn_mfma_f32_16x16x32_bf16(ah[m], bl[n], acc[m][n], 0, 0, 0);
                acc[m][n] = __builtin_amdgcn_mfma_f32_16x16x32_bf16(al[m], bh[n], acc[m][n], 0, 0, 0);
            }
    }

    #pragma unroll
    for (int n = 0; n < 6; ++n) {
        int colg = w * 96 + n * 16 + l15;
        float bias = bcat[colg];
        #pragma unroll
        for (int m = 0; m < 2; ++m) {
            int rbase = row0 + m * 16 + lh * 4;
            #pragma unroll
            for (int j = 0; j < 4; ++j) {
                int rr = rbase + j;
                if (rr < N)
                    pack[(size_t)rr * 384 + colg] = __float2half_rn(acc[m][n][j] + bias);
            }
        }
    }
}

// ---------------------------------------------------------------------------
// k_rowedge: one wave per destination row; two 32-lane halves each own an
// interleaved edge stream, unrolled x2 (4 gather chains in flight).
// Lane hl owns channels [4hl,4hl+3]; head = hl>>3 (3-level shfl reduce).
// pack is fp16: K at half-offset 128, V at 256 (8B per lane per load).
// ---------------------------------------------------------------------------
__global__ __launch_bounds__(512, 4) void k_rowedge(
    const int* __restrict__ csr_col, const int* __restrict__ row_start,
    const __half* __restrict__ pack, const unsigned char* __restrict__ group8,
    const float* __restrict__ Sg, float* __restrict__ outacc,
    double* __restrict__ head_sum, int N) {
    __shared__ float4 sg4[64 * 32];   // Sg fp32 [group][chunk], 32 KB
    __shared__ float hsum[4];

    const int tid = threadIdx.x;
    for (int i = tid; i < 64 * 32; i += 512) sg4[i] = ((const float4*)Sg)[i];
    if (tid < 4) hsum[tid] = 0.f;
    __syncthreads();

    const int wid = tid >> 6;
    const int l = tid & 63;
    const int half = l >> 5;
    const int hl = l & 31;
    const int row = blockIdx.x * 8 + wid;

    const float inv_scale = 0.05892556509887896f;  // 1/(3*sqrt(32))
    float lsum = 0.f;

    if (row < N) {
        const __half* rp = pack + (size_t)row * 384;
        float4 q = ld4h(rp + 4 * hl);
        float4 sr = sg4[(int)group8[row] * 32 + hl];
        float4 qs = make_float4(q.x + sr.x, q.y + sr.y, q.z + sr.z, q.w + sr.w);
        float4 acc = make_float4(0.f, 0.f, 0.f, 0.f);

        const int beg = row_start[row];
        const int end = row_start[row + 1];
        for (int i = beg + half; i < end; i += 4) {
            const int iB = i + 2;
            const bool vB = iB < end;
            int colA = csr_col[i];
            int colB = vB ? csr_col[iB] : colA;
            const __half* cpA = pack + (size_t)colA * 384;
            const __half* cpB = pack + (size_t)colB * 384;
            float4 kkA = ld4h(cpA + 128 + 4 * hl);
            float4 vvA = ld4h(cpA + 256 + 4 * hl);
            float4 kkB = ld4h(cpB + 128 + 4 * hl);
            float4 vvB = ld4h(cpB + 256 + 4 * hl);
            float4 scA = sg4[(int)group8[colA] * 32 + hl];
            float4 scB = sg4[(int)group8[colB] * 32 + hl];

            float tA = qs.x * kkA.x + qs.y * kkA.y + qs.z * kkA.z + qs.w * kkA.w
                     + q.x * scA.x + q.y * scA.y + q.z * scA.z + q.w * scA.w;
            float tB = qs.x * kkB.x + qs.y * kkB.y + qs.z * kkB.z + qs.w * kkB.w
                     + q.x * scB.x + q.y * scB.y + q.z * scB.z + q.w * scB.w;
            tA += __shfl_xor(tA, 1);  tB += __shfl_xor(tB, 1);
            tA += __shfl_xor(tA, 2);  tB += __shfl_xor(tB, 2);
            tA += __shfl_xor(tA, 4);  tB += __shfl_xor(tB, 4);

            float aA = tA * inv_scale;
            aA = (aA >= 0.f) ? aA : 0.2f * aA;    // leaky_relu(0.2)
            float aB = tB * inv_scale;
            aB = (aB >= 0.f) ? aB : 0.2f * aB;
            float pA = expf(aA);
            float pB = vB ? expf(aB) : 0.f;

            if ((hl & 7) == 0) lsum += pA + pB;
            acc.x += pA * vvA.x + pB * vvB.x;
            acc.y += pA * vvA.y + pB * vvB.y;
            acc.z += pA * vvA.z + pB * vvB.z;
            acc.w += pA * vvA.w + pB * vvB.w;
        }

        acc.x += __shfl_xor(acc.x, 32);
        acc.y += __shfl_xor(acc.y, 32);
        acc.z += __shfl_xor(acc.z, 32);
        acc.w += __shfl_xor(acc.w, 32);
        if (half == 0)
            ((float4*)(outacc + (size_t)row * 128))[hl] = acc;
    }

    if ((l & 7) == 0) atomicAdd(&hsum[(l & 31) >> 3], lsum);
    __syncthreads();
    if (tid < 4) atomicAdd(&head_sum[tid], (double)hsum[tid]);
}

// ---------------------------------------------------------------------------
// k_out_mfma: out = (outacc * 1/head_sum) @ Wo + bo + x  (split-bf16 MFMA).
// outacc aliases out (d_out): block stages its own 32 rows before overwrite.
// Wave w -> cols [32w, 32w+32). Wo fragments at fk 96..127 in wfrag.
// ---------------------------------------------------------------------------
__global__ __launch_bounds__(256) void k_out_mfma(
    const float* __restrict__ outacc, const double* __restrict__ head_sum,
    const unsigned short* __restrict__ wfrag, const float* __restrict__ bcat,
    const float* __restrict__ x, float* __restrict__ out, int N) {
    __shared__ __align__(16) unsigned short hi_lds[32 * 128];
    __shared__ __align__(16) unsigned short lo_lds[32 * 128];

    const int tid = threadIdx.x;
    const int row0 = blockIdx.x * 32;

    float inv[4];
    #pragma unroll
    for (int h = 0; h < 4; ++h) inv[h] = (float)(1.0 / head_sum[h]);

    const float4* o4 = (const float4*)outacc;
    #pragma unroll
    for (int t = tid; t < 512; t += 256) {
        int r = t >> 4, u = t & 15;
        int row = row0 + r;
        float4 a = make_float4(0.f, 0.f, 0.f, 0.f), b = a;
        if (row < N) {
            a = o4[(size_t)row * 32 + u * 2];
            b = o4[(size_t)row * 32 + u * 2 + 1];
        }
        float s = inv[u >> 2];   // channels u*8..u*8+7 all in head u/4
        float v[8] = {a.x * s, a.y * s, a.z * s, a.w * s,
                      b.x * s, b.y * s, b.z * s, b.w * s};
        bfx8 hv, lv;
        #pragma unroll
        for (int e = 0; e < 8; ++e) {
            unsigned short h = f2bf(v[e]);
            hv[e] = (short)h;
            lv[e] = (short)f2bf(v[e] - bf2f(h));
        }
        int su = r * 16 + (u ^ (r & 7));
        ((bfx8*)hi_lds)[su] = hv;
        ((bfx8*)lo_lds)[su] = lv;
    }
    __syncthreads();

    const int w = tid >> 6;
    const int l = tid & 63;
    const int l15 = l & 15, lh = l >> 4;

    f32x4 zero = {0.f, 0.f, 0.f, 0.f};
    f32x4 acc[2][2];
    #pragma unroll
    for (int m = 0; m < 2; ++m)
        #pragma unroll
        for (int n = 0; n < 2; ++n) acc[m][n] = zero;

    const bfx8* wf = (const bfx8*)wfrag;
    const bfx8* hi8 = (const bfx8*)hi_lds;
    const bfx8* lo8 = (const bfx8*)lo_lds;

    #pragma unroll
    for (int ks = 0; ks < 4; ++ks) {
        bfx8 bh[2], bl[2];
        #pragma unroll
        for (int n = 0; n < 2; ++n) {
            int fk = 96 + (w * 2 + n) * 4 + ks;
            bh[n] = wf[fk * 64 + l];
            bl[n] = wf[8192 + fk * 64 + l];
        }
        bfx8 ah[2], al[2];
        #pragma unroll
        for (int m = 0; m < 2; ++m) {
            int r = m * 16 + l15;
            int su = r * 16 + ((ks * 4 + lh) ^ (r & 7));
            ah[m] = hi8[su];
            al[m] = lo8[su];
        }
        #pragma unroll
        for (int m = 0; m < 2; ++m)
            #pragma unroll
            for (int n = 0; n < 2; ++n) {
                acc[m][n] = __builtin_amdgcn_mfma_f32_16x16x32_bf16(ah[m], bh[n], acc[m][n], 0, 0, 0);
                acc[m][n] = __builtin_amdgcn_mfma_f32_16x16x32_bf16(ah[m], bl[n], acc[m][n], 0, 0, 0);
                acc[m][n] = __builtin_amdgcn_mfma_f32_16x16x32_bf16(al[m], bh[n], acc[m][n], 0, 0, 0);
            }
    }

    #pragma unroll
    for (int n = 0; n < 2; ++n) {
        int colg = w * 32 + n * 16 + l15;
        float bias = bcat[384 + colg];
        #pragma unroll
        for (int m = 0; m < 2; ++m) {
            int rbase = row0 + m * 16 + lh * 4;
            #pragma unroll
            for (int j = 0; j < 4; ++j) {
                int rr = rbase + j;
                if (rr < N)
                    out[(size_t)rr * 128 + colg] =
                        acc[m][n][j] + bias + x[(size_t)rr * 128 + colg];
            }
        }
    }
}

// ---------------------------------------------------------------------------
extern "C" void kernel_launch(void* const* d_in, const int* in_sizes, int n_in,
                              void* d_out, int out_size, void* d_ws, size_t ws_size,
                              hipStream_t stream) {
    const float* x     = (const float*)d_in[0];
    const int*   eidx  = (const int*)d_in[1];
    const float* sent  = (const float*)d_in[2];
    const int*   batch = (const int*)d_in[3];
    const float* Wq = (const float*)d_in[4];
    const float* bq = (const float*)d_in[5];
    const float* Wk = (const float*)d_in[6];
    const float* bk = (const float*)d_in[7];
    const float* Wv = (const float*)d_in[8];
    const float* bv = (const float*)d_in[9];
    const float* Ws = (const float*)d_in[10];
    const float* bs = (const float*)d_in[11];
    const float* Wo = (const float*)d_in[12];
    const float* bo = (const float*)d_in[13];

    const int N = in_sizes[0] / 128;   // 50000
    const int E = in_sizes[1] / 2;     // 800000

    // ---- workspace layout (256B-aligned slots) ----
    char* ws = (char*)d_ws;
    size_t off = 0;
    auto alloc = [&](size_t bytes) {
        char* p = ws + off;
        off += (bytes + 255) & ~(size_t)255;
        return p;
    };
    float*  Sg        = (float*)alloc(64 * 128 * sizeof(float));
    double* head_sum  = (double*)alloc(4 * sizeof(double));
    unsigned char* group8 = (unsigned char*)alloc((size_t)N);
    int* counts    = (int*)alloc((size_t)N * sizeof(int));
    int* row_start = (int*)alloc(((size_t)N + 1) * sizeof(int));
    int* cursor    = (int*)alloc((size_t)N * sizeof(int));
    int* csr_col   = (int*)alloc((size_t)E * sizeof(int));
    unsigned short* wfrag = (unsigned short*)alloc(2 * 128 * 64 * 8 * sizeof(unsigned short)); // 256 KB
    float* bcat    = (float*)alloc(512 * sizeof(float));
    __half* pack   = (__half*)alloc((size_t)N * 384 * sizeof(__half));  // 38.4 MB

    float* outacc = (float*)d_out;   // aliased; k_rowedge writes every row once

    hipMemsetAsync(counts, 0, (size_t)N * sizeof(int), stream);
    hipMemsetAsync(head_sum, 0, 4 * sizeof(double), stream);

    const int eb = (E + 255) / 256;
    k_prep<<<64 + eb, 256, 0, stream>>>(sent, Ws, bs, Sg, Wq, Wk, Wv, Wo,
                                        bq, bk, bv, bo, wfrag, bcat,
                                        eidx, counts, E);
    k_scan<<<1, 1024, 0, stream>>>(counts, row_start, cursor, N);
    k_scatter<<<eb, 256, 0, stream>>>(eidx, cursor, csr_col, E);

    const int qkv_blocks = (N + 31) / 32;
    const int row_blocks = (N + 7) / 8;
    k_qkv_mfma<<<qkv_blocks, 256, 0, stream>>>(x, batch, wfrag, bcat,
                                               pack, group8, N);
    k_rowedge<<<row_blocks, 512, 0, stream>>>(csr_col, row_start, pack,
                                              group8, Sg, outacc, head_sum, N);
    k_out_mfma<<<qkv_blocks, 256, 0, stream>>>(outacc, head_sum, wfrag, bcat,
                                               x, (float*)d_out, N);
}